// Round 11
// baseline (2265.700 us; speedup 1.0000x reference)
//
#include <hip/hip_runtime.h>
#include <hip/hip_bf16.h>
#include <hip/hip_cooperative_groups.h>

namespace cg = cooperative_groups;

#define N_NODES 50000
#define N_EDGES 600000
#define N_GRAPHS 256
#define C 128
#define NB 196            // ceil(N_NODES/256) scan blocks
#define GBLK 1024         // cooperative grid: 256 CU x 4 blocks/CU
#define GTHR (GBLK * 256)
// fallback k_prep block ranges
#define PB_DEG 2344
#define PB_XS  6250
#define PB_WS  512

typedef unsigned short ushort;
typedef unsigned int uint;
typedef __attribute__((ext_vector_type(8))) short bfrag8;
typedef __attribute__((ext_vector_type(4))) float facc4;

// bf16 helpers (bit-level, RNE)
__device__ __forceinline__ ushort f2bf(float v) {
    uint u = __float_as_uint(v);
    u += 0x7FFFu + ((u >> 16) & 1u);
    return (ushort)(u >> 16);
}
__device__ __forceinline__ float bf2f(ushort u) {
    return __uint_as_float(((uint)u) << 16);
}
__device__ __forceinline__ void fsplit(float v, ushort& h, ushort& l) {
    h = f2bf(v);
    l = f2bf(v - bf2f(h));
}

struct WPtrs { const float* wl[4]; const float* wr[4]; };

struct MegaP {
    const float* x;
    const int* src; const int* tgt;
    const int* root; const int* batch;
    WPtrs wp;
    const float* bl[4];
    const float* wcls; const float* bcls;
    ushort* Ahi; ushort* Alo; ushort* BTh; ushort* BTl;
    int* deg; int* fill; float* dinv;
    int* rowptr; int* csr_src; int* bsum; int* gstart;
    float* out;
};

// ================================================================ MEGA KERNEL
// All phases in one cooperative launch; compute bodies verbatim from r10.
// LDS: As/Bs pad 38 (19-word odd stride: conflict-free, 38912B -> 4 blocks/CU).
__global__ void __launch_bounds__(256, 4) k_mega(MegaP p) {
    cg::grid_group grid = cg::this_grid();
    __shared__ __align__(16) short As[2][128][38];
    __shared__ __align__(16) short Bs[2][128][38];
    const int tid = threadIdx.x;
    const int bid = blockIdx.x;
    const int gtid = bid * 256 + tid;
    const int wave = tid >> 6, lane = tid & 63;
    const int l15 = lane & 15, lk = (lane >> 4) * 8;

    // ---- P0: zero deg + fill
    for (int i = gtid; i < N_NODES; i += GTHR) p.deg[i] = 0;
    for (int i = gtid; i < N_NODES; i += GTHR) p.fill[i] = 0;
    grid.sync();

    // ---- P1: deg histogram + xsplit + wsplit + gstart
    for (int e = gtid; e < N_EDGES; e += GTHR) atomicAdd(&p.deg[p.tgt[e]], 1);
    for (int gid = gtid; gid < N_NODES * 32; gid += GTHR) {
        int n = gid >> 5, c4 = (gid & 31) << 2;
        float4 v = *(const float4*)(p.x + (size_t)n * C + c4);
        ushort4 h, l;
        fsplit(v.x, h.x, l.x); fsplit(v.y, h.y, l.y);
        fsplit(v.z, h.z, l.z); fsplit(v.w, h.w, l.w);
        *(ushort4*)(p.Ahi + (size_t)n * 256 + 128 + c4) = h;
        *(ushort4*)(p.Alo + (size_t)n * 256 + 128 + c4) = l;
    }
    for (int gid = gtid; gid < 4 * 128 * 256; gid += GTHR) {
        int l = gid >> 15;
        int rem = gid & 32767;
        int n = rem >> 8, k = rem & 255;
        float v = (k < 128) ? p.wp.wl[l][n * 128 + k] : p.wp.wr[l][n * 128 + (k - 128)];
        ushort h, lo;
        fsplit(v, h, lo);
        p.BTh[gid] = h;
        p.BTl[gid] = lo;
    }
    if (bid == 0) {
        int g = tid;
        int lo = 0, hi = N_NODES;
        while (lo < hi) {
            int mid = (lo + hi) >> 1;
            if (p.batch[mid] < g) lo = mid + 1;
            else hi = mid;
        }
        p.gstart[g] = lo;
        if (tid == 0) p.gstart[N_GRAPHS] = N_NODES;
    }
    grid.sync();

    // ---- P2: scan1 (block sums + dinv)
    if (bid < NB) {
        int* ws = (int*)&Bs[0][0][0];
        int idx = bid * 256 + tid;
        int v = (idx < N_NODES) ? p.deg[idx] : 0;
        if (idx < N_NODES) p.dinv[idx] = 1.0f / fmaxf((float)v, 1.0f);
        int s = v;
#pragma unroll
        for (int off = 1; off < 64; off <<= 1) s += __shfl_xor(s, off);
        if ((tid & 63) == 0) ws[tid >> 6] = s;
        __syncthreads();
        if (tid == 0) p.bsum[bid] = ws[0] + ws[1] + ws[2] + ws[3];
    }
    grid.sync();

    // ---- P3: scan2 (global offset + local scan -> rowptr)
    if (bid < NB) {
        int* red = (int*)&Bs[0][0][0];
        int* ws = red + 4;
        int bv = (tid < NB && tid < bid) ? p.bsum[tid] : 0;
#pragma unroll
        for (int off = 1; off < 64; off <<= 1) bv += __shfl_xor(bv, off);
        if (lane == 0) red[wave] = bv;
        __syncthreads();
        const int boff = red[0] + red[1] + red[2] + red[3];
        int idx = bid * 256 + tid;
        int v = (idx < N_NODES) ? p.deg[idx] : 0;
        int incl = v;
#pragma unroll
        for (int off = 1; off < 64; off <<= 1) {
            int u = __shfl_up(incl, off);
            if (lane >= off) incl += u;
        }
        if (lane == 63) ws[wave] = incl;
        __syncthreads();
        int wo = 0;
        if (wave > 0) wo += ws[0];
        if (wave > 1) wo += ws[1];
        if (wave > 2) wo += ws[2];
        if (idx < N_NODES) p.rowptr[idx] = boff + wo + incl - v;
        if (bid == 0 && tid == 0) p.rowptr[N_NODES] = N_EDGES;
    }
    grid.sync();

    // ---- P4: CSR fill
    for (int e = gtid; e < N_EDGES; e += GTHR) {
        int d = p.tgt[e];
        int pos = atomicAdd(&p.fill[d], 1);
        p.csr_src[p.rowptr[d] + pos] = p.src[e];
    }
    grid.sync();

    // ---- 4 layers: gather -> sync -> gemm -> sync
    for (int l = 0; l < 4; l++) {
        const ushort* BThl = p.BTh + l * 32768;
        const ushort* BTll = p.BTl + l * 32768;
        const float* bl = p.bl[l];

        // gather (r10 body: 32 lanes/node, ushort4, 4-edge unroll)
        for (int vb = bid; vb < (N_NODES + 7) / 8; vb += GBLK) {
            int node = vb * 8 + (tid >> 5);
            if (node < N_NODES) {
                int lane32 = tid & 31;
                int c4 = lane32 << 2;
                int s = p.rowptr[node], e = p.rowptr[node + 1];
                float a0 = 0.f, a1 = 0.f, a2 = 0.f, a3 = 0.f;
                int j = s;
                for (; j + 3 < e; j += 4) {
                    int s0 = p.csr_src[j], s1 = p.csr_src[j + 1];
                    int s2 = p.csr_src[j + 2], s3 = p.csr_src[j + 3];
                    ushort4 h0 = *(const ushort4*)(p.Ahi + (size_t)s0 * 256 + 128 + c4);
                    ushort4 l0 = *(const ushort4*)(p.Alo + (size_t)s0 * 256 + 128 + c4);
                    ushort4 h1 = *(const ushort4*)(p.Ahi + (size_t)s1 * 256 + 128 + c4);
                    ushort4 l1 = *(const ushort4*)(p.Alo + (size_t)s1 * 256 + 128 + c4);
                    ushort4 h2 = *(const ushort4*)(p.Ahi + (size_t)s2 * 256 + 128 + c4);
                    ushort4 l2 = *(const ushort4*)(p.Alo + (size_t)s2 * 256 + 128 + c4);
                    ushort4 h3 = *(const ushort4*)(p.Ahi + (size_t)s3 * 256 + 128 + c4);
                    ushort4 l3 = *(const ushort4*)(p.Alo + (size_t)s3 * 256 + 128 + c4);
                    a0 += (bf2f(h0.x) + bf2f(l0.x)) + (bf2f(h1.x) + bf2f(l1.x))
                        + (bf2f(h2.x) + bf2f(l2.x)) + (bf2f(h3.x) + bf2f(l3.x));
                    a1 += (bf2f(h0.y) + bf2f(l0.y)) + (bf2f(h1.y) + bf2f(l1.y))
                        + (bf2f(h2.y) + bf2f(l2.y)) + (bf2f(h3.y) + bf2f(l3.y));
                    a2 += (bf2f(h0.z) + bf2f(l0.z)) + (bf2f(h1.z) + bf2f(l1.z))
                        + (bf2f(h2.z) + bf2f(l2.z)) + (bf2f(h3.z) + bf2f(l3.z));
                    a3 += (bf2f(h0.w) + bf2f(l0.w)) + (bf2f(h1.w) + bf2f(l1.w))
                        + (bf2f(h2.w) + bf2f(l2.w)) + (bf2f(h3.w) + bf2f(l3.w));
                }
                for (; j < e; j++) {
                    int s0 = p.csr_src[j];
                    ushort4 h0 = *(const ushort4*)(p.Ahi + (size_t)s0 * 256 + 128 + c4);
                    ushort4 l0 = *(const ushort4*)(p.Alo + (size_t)s0 * 256 + 128 + c4);
                    a0 += bf2f(h0.x) + bf2f(l0.x);
                    a1 += bf2f(h0.y) + bf2f(l0.y);
                    a2 += bf2f(h0.z) + bf2f(l0.z);
                    a3 += bf2f(h0.w) + bf2f(l0.w);
                }
                float sc = p.dinv[node];
                a0 *= sc; a1 *= sc; a2 *= sc; a3 *= sc;
                ushort4 h, lo4;
                fsplit(a0, h.x, lo4.x); fsplit(a1, h.y, lo4.y);
                fsplit(a2, h.z, lo4.z); fsplit(a3, h.w, lo4.w);
                *(ushort4*)(p.Ahi + (size_t)node * 256 + c4) = h;
                *(ushort4*)(p.Alo + (size_t)node * 256 + c4) = lo4;
            }
        }
        grid.sync();

        // gemm (r10/r5 body: 128x128, 4 waves 2x2 of 64x64, pipelined staging)
        if (bid < (N_NODES + 127) / 128) {
            const int m0 = bid * 128;
            const int wm = (wave & 1) * 64;
            const int wn = (wave >> 1) * 64;
            const int sr = tid >> 1;
            const int sc = (tid & 1) * 16;
            int garow = m0 + sr; if (garow >= N_NODES) garow = N_NODES - 1;
            const ushort* pAh = p.Ahi + (size_t)garow * 256 + sc;
            const ushort* pAl = p.Alo + (size_t)garow * 256 + sc;
            const ushort* pBh = BThl + sr * 256 + sc;
            const ushort* pBl = BTll + sr * 256 + sc;

            bfrag8 rAh0, rAh1, rAl0, rAl1, rBh0, rBh1, rBl0, rBl1;
#define LOADSTEP(K0) do { \
        rAh0 = *(const bfrag8*)(pAh + (K0));     rAh1 = *(const bfrag8*)(pAh + (K0) + 8); \
        rAl0 = *(const bfrag8*)(pAl + (K0));     rAl1 = *(const bfrag8*)(pAl + (K0) + 8); \
        rBh0 = *(const bfrag8*)(pBh + (K0));     rBh1 = *(const bfrag8*)(pBh + (K0) + 8); \
        rBl0 = *(const bfrag8*)(pBl + (K0));     rBl1 = *(const bfrag8*)(pBl + (K0) + 8); \
    } while (0)

            LOADSTEP(0);
            facc4 acc[4][4] = {};
#pragma unroll
            for (int s = 0; s < 8; s++) {
                *(bfrag8*)&As[0][sr][sc]     = rAh0;  *(bfrag8*)&As[0][sr][sc + 8] = rAh1;
                *(bfrag8*)&As[1][sr][sc]     = rAl0;  *(bfrag8*)&As[1][sr][sc + 8] = rAl1;
                *(bfrag8*)&Bs[0][sr][sc]     = rBh0;  *(bfrag8*)&Bs[0][sr][sc + 8] = rBh1;
                *(bfrag8*)&Bs[1][sr][sc]     = rBl0;  *(bfrag8*)&Bs[1][sr][sc + 8] = rBl1;
                __syncthreads();
                if (s < 7) LOADSTEP((s + 1) * 32);
                bfrag8 a[2][4], b[2][4];
#pragma unroll
                for (int t = 0; t < 4; t++) {
                    a[0][t] = *(const bfrag8*)&As[0][wm + t * 16 + l15][lk];
                    a[1][t] = *(const bfrag8*)&As[1][wm + t * 16 + l15][lk];
                    b[0][t] = *(const bfrag8*)&Bs[0][wn + t * 16 + l15][lk];
                    b[1][t] = *(const bfrag8*)&Bs[1][wn + t * 16 + l15][lk];
                }
#pragma unroll
                for (int mt = 0; mt < 4; mt++)
#pragma unroll
                    for (int nt = 0; nt < 4; nt++) {
                        acc[mt][nt] = __builtin_amdgcn_mfma_f32_16x16x32_bf16(a[0][mt], b[0][nt], acc[mt][nt], 0, 0, 0);
                        acc[mt][nt] = __builtin_amdgcn_mfma_f32_16x16x32_bf16(a[0][mt], b[1][nt], acc[mt][nt], 0, 0, 0);
                        acc[mt][nt] = __builtin_amdgcn_mfma_f32_16x16x32_bf16(a[1][mt], b[0][nt], acc[mt][nt], 0, 0, 0);
                    }
                __syncthreads();
            }
#undef LOADSTEP
            const int r4 = (lane >> 4) * 4;
#pragma unroll
            for (int mt = 0; mt < 4; mt++) {
#pragma unroll
                for (int nt = 0; nt < 4; nt++) {
                    int col = wn + nt * 16 + l15;
                    float bias = bl[col];
#pragma unroll
                    for (int r = 0; r < 4; r++) {
                        int grow = m0 + wm + mt * 16 + r4 + r;
                        if (grow < N_NODES) {
                            float v = fmaxf(acc[mt][nt][r] + bias, 0.f);
                            ushort h, lo;
                            fsplit(v, h, lo);
                            p.Ahi[(size_t)grow * 256 + 128 + col] = h;
                            p.Alo[(size_t)grow * 256 + 128 + col] = lo;
                        }
                    }
                }
            }
        }
        grid.sync();
    }

    // ---- head: mean-pool + classifier (one block per graph)
    if (bid < N_GRAPHS) {
        float* gm = (float*)&As[0][0][0];
        float* part = gm + 128;
        float* red = part + 128;
        const int g = bid;
        const int c = tid & 127, ph = tid >> 7;
        int s = p.gstart[g], e = p.gstart[g + 1];
        float sum = 0.f;
        for (int n = s + ph; n < e; n += 2) {
            size_t o = (size_t)n * 256 + 128 + c;
            sum += bf2f(p.Ahi[o]) + bf2f(p.Alo[o]);
        }
        if (ph) part[c] = sum;
        __syncthreads();
        if (!ph) gm[c] = (sum + part[c]) / fmaxf((float)(e - s), 1.0f);
        __syncthreads();
        float v;
        if (tid < 128) {
            size_t o = (size_t)p.root[g] * 256 + 128 + tid;
            v = bf2f(p.Ahi[o]) + bf2f(p.Alo[o]);
        } else {
            v = gm[tid - 128];
        }
        float p0 = v * p.wcls[tid];
        float p1 = v * p.wcls[256 + tid];
#pragma unroll
        for (int off = 32; off; off >>= 1) {
            p0 += __shfl_down(p0, off);
            p1 += __shfl_down(p1, off);
        }
        if ((tid & 63) == 0) { red[wave] = p0; red[4 + wave] = p1; }
        __syncthreads();
        if (tid == 0) {
            p.out[g * 2 + 0] = red[0] + red[1] + red[2] + red[3] + p.bcls[0];
            p.out[g * 2 + 1] = red[4] + red[5] + red[6] + red[7] + p.bcls[1];
        }
    }
}

// ================================================================ FALLBACK (r10 kernels, verbatim)
__global__ __launch_bounds__(256) void k_prep(const int* __restrict__ tgt,
                                              int* __restrict__ deg,
                                              const float* __restrict__ x,
                                              ushort* __restrict__ Ahi,
                                              ushort* __restrict__ Alo,
                                              WPtrs wp,
                                              ushort* __restrict__ BTh,
                                              ushort* __restrict__ BTl,
                                              const int* __restrict__ batch,
                                              int* __restrict__ gstart) {
    const int b = blockIdx.x, t = threadIdx.x;
    if (b < PB_DEG) {
        int e = b * 256 + t;
        if (e < N_EDGES) atomicAdd(&deg[tgt[e]], 1);
    } else if (b < PB_DEG + PB_XS) {
        int gid = (b - PB_DEG) * 256 + t;
        int n = gid >> 5, c4 = (gid & 31) << 2;
        float4 v = *(const float4*)(x + (size_t)n * C + c4);
        ushort4 h, l;
        fsplit(v.x, h.x, l.x); fsplit(v.y, h.y, l.y);
        fsplit(v.z, h.z, l.z); fsplit(v.w, h.w, l.w);
        *(ushort4*)(Ahi + (size_t)n * 256 + 128 + c4) = h;
        *(ushort4*)(Alo + (size_t)n * 256 + 128 + c4) = l;
    } else if (b < PB_DEG + PB_XS + PB_WS) {
        int gid = (b - PB_DEG - PB_XS) * 256 + t;
        int l = gid >> 15;
        int rem = gid & 32767;
        int n = rem >> 8, k = rem & 255;
        float v = (k < 128) ? wp.wl[l][n * 128 + k] : wp.wr[l][n * 128 + (k - 128)];
        ushort h, lo;
        fsplit(v, h, lo);
        BTh[gid] = h;
        BTl[gid] = lo;
    } else {
        int g = t;
        int lo = 0, hi = N_NODES;
        while (lo < hi) {
            int mid = (lo + hi) >> 1;
            if (batch[mid] < g) lo = mid + 1;
            else hi = mid;
        }
        gstart[g] = lo;
        if (t == 0) gstart[N_GRAPHS] = N_NODES;
    }
}

__global__ __launch_bounds__(256) void k_scan1(const int* __restrict__ deg,
                                               int* __restrict__ bsum,
                                               float* __restrict__ dinv) {
    __shared__ int ws[4];
    int idx = blockIdx.x * 256 + threadIdx.x;
    int v = (idx < N_NODES) ? deg[idx] : 0;
    if (idx < N_NODES) dinv[idx] = 1.0f / fmaxf((float)v, 1.0f);
    int s = v;
#pragma unroll
    for (int off = 1; off < 64; off <<= 1) s += __shfl_xor(s, off);
    if ((threadIdx.x & 63) == 0) ws[threadIdx.x >> 6] = s;
    __syncthreads();
    if (threadIdx.x == 0) bsum[blockIdx.x] = ws[0] + ws[1] + ws[2] + ws[3];
}

__global__ __launch_bounds__(256) void k_scan2(const int* __restrict__ deg,
                                               const int* __restrict__ bsum,
                                               int* __restrict__ rowptr) {
    __shared__ int red[4];
    __shared__ int ws[4];
    const int b = blockIdx.x, t = threadIdx.x;
    const int lane = t & 63, w = t >> 6;
    int bv = (t < NB && t < b) ? bsum[t] : 0;
#pragma unroll
    for (int off = 1; off < 64; off <<= 1) bv += __shfl_xor(bv, off);
    if (lane == 0) red[w] = bv;
    __syncthreads();
    const int boff = red[0] + red[1] + red[2] + red[3];
    int idx = b * 256 + t;
    int v = (idx < N_NODES) ? deg[idx] : 0;
    int incl = v;
#pragma unroll
    for (int off = 1; off < 64; off <<= 1) {
        int u = __shfl_up(incl, off);
        if (lane >= off) incl += u;
    }
    if (lane == 63) ws[w] = incl;
    __syncthreads();
    int wo = 0;
    if (w > 0) wo += ws[0];
    if (w > 1) wo += ws[1];
    if (w > 2) wo += ws[2];
    if (idx < N_NODES) rowptr[idx] = boff + wo + incl - v;
    if (b == 0 && t == 0) rowptr[N_NODES] = N_EDGES;
}

__global__ void k_fill(const int* __restrict__ src, const int* __restrict__ tgt,
                       const int* __restrict__ rowptr, int* __restrict__ fill,
                       int* __restrict__ csr_src) {
    int e = blockIdx.x * blockDim.x + threadIdx.x;
    if (e >= N_EDGES) return;
    int d = tgt[e];
    int pos = atomicAdd(&fill[d], 1);
    csr_src[rowptr[d] + pos] = src[e];
}

__global__ __launch_bounds__(256) void k_gather(const ushort* __restrict__ Ahi_r,
                                                const ushort* __restrict__ Alo_r,
                                                ushort* __restrict__ Ahi_w,
                                                ushort* __restrict__ Alo_w,
                                                const int* __restrict__ csr_src,
                                                const int* __restrict__ rowptr,
                                                const float* __restrict__ dinv) {
    int node = blockIdx.x * 8 + (threadIdx.x >> 5);
    if (node >= N_NODES) return;
    int lane = threadIdx.x & 31;
    int c4 = lane << 2;
    int s = rowptr[node], e = rowptr[node + 1];
    float a0 = 0.f, a1 = 0.f, a2 = 0.f, a3 = 0.f;
    int j = s;
    for (; j + 3 < e; j += 4) {
        int s0 = csr_src[j], s1 = csr_src[j + 1];
        int s2 = csr_src[j + 2], s3 = csr_src[j + 3];
        ushort4 h0 = *(const ushort4*)(Ahi_r + (size_t)s0 * 256 + 128 + c4);
        ushort4 l0 = *(const ushort4*)(Alo_r + (size_t)s0 * 256 + 128 + c4);
        ushort4 h1 = *(const ushort4*)(Ahi_r + (size_t)s1 * 256 + 128 + c4);
        ushort4 l1 = *(const ushort4*)(Alo_r + (size_t)s1 * 256 + 128 + c4);
        ushort4 h2 = *(const ushort4*)(Ahi_r + (size_t)s2 * 256 + 128 + c4);
        ushort4 l2 = *(const ushort4*)(Alo_r + (size_t)s2 * 256 + 128 + c4);
        ushort4 h3 = *(const ushort4*)(Ahi_r + (size_t)s3 * 256 + 128 + c4);
        ushort4 l3 = *(const ushort4*)(Alo_r + (size_t)s3 * 256 + 128 + c4);
        a0 += (bf2f(h0.x) + bf2f(l0.x)) + (bf2f(h1.x) + bf2f(l1.x))
            + (bf2f(h2.x) + bf2f(l2.x)) + (bf2f(h3.x) + bf2f(l3.x));
        a1 += (bf2f(h0.y) + bf2f(l0.y)) + (bf2f(h1.y) + bf2f(l1.y))
            + (bf2f(h2.y) + bf2f(l2.y)) + (bf2f(h3.y) + bf2f(l3.y));
        a2 += (bf2f(h0.z) + bf2f(l0.z)) + (bf2f(h1.z) + bf2f(l1.z))
            + (bf2f(h2.z) + bf2f(l2.z)) + (bf2f(h3.z) + bf2f(l3.z));
        a3 += (bf2f(h0.w) + bf2f(l0.w)) + (bf2f(h1.w) + bf2f(l1.w))
            + (bf2f(h2.w) + bf2f(l2.w)) + (bf2f(h3.w) + bf2f(l3.w));
    }
    for (; j < e; j++) {
        int s0 = csr_src[j];
        ushort4 h0 = *(const ushort4*)(Ahi_r + (size_t)s0 * 256 + 128 + c4);
        ushort4 l0 = *(const ushort4*)(Alo_r + (size_t)s0 * 256 + 128 + c4);
        a0 += bf2f(h0.x) + bf2f(l0.x);
        a1 += bf2f(h0.y) + bf2f(l0.y);
        a2 += bf2f(h0.z) + bf2f(l0.z);
        a3 += bf2f(h0.w) + bf2f(l0.w);
    }
    float sc = dinv[node];
    a0 *= sc; a1 *= sc; a2 *= sc; a3 *= sc;
    ushort4 h, l;
    fsplit(a0, h.x, l.x); fsplit(a1, h.y, l.y);
    fsplit(a2, h.z, l.z); fsplit(a3, h.w, l.w);
    *(ushort4*)(Ahi_w + (size_t)node * 256 + c4) = h;
    *(ushort4*)(Alo_w + (size_t)node * 256 + c4) = l;
}

__global__ __launch_bounds__(256) void k_gemm(const ushort* __restrict__ Ahi,
                                              const ushort* __restrict__ Alo,
                                              const ushort* __restrict__ BTh,
                                              const ushort* __restrict__ BTl,
                                              const float* __restrict__ bl,
                                              ushort* __restrict__ Hhi,
                                              ushort* __restrict__ Hlo) {
    __shared__ short As[2][128][38];
    __shared__ short Bs[2][128][38];
    const int tid = threadIdx.x;
    const int wave = tid >> 6, lane = tid & 63;
    const int m0 = blockIdx.x * 128;
    const int wm = (wave & 1) * 64;
    const int wn = (wave >> 1) * 64;
    const int l15 = lane & 15, lk = (lane >> 4) * 8;

    const int sr = tid >> 1;
    const int sc = (tid & 1) * 16;
    int garow = m0 + sr; if (garow >= N_NODES) garow = N_NODES - 1;
    const ushort* pAh = Ahi + (size_t)garow * 256 + sc;
    const ushort* pAl = Alo + (size_t)garow * 256 + sc;
    const ushort* pBh = BTh + sr * 256 + sc;
    const ushort* pBl = BTl + sr * 256 + sc;

    bfrag8 rAh0, rAh1, rAl0, rAl1, rBh0, rBh1, rBl0, rBl1;
#define LOADSTEP(K0) do { \
        rAh0 = *(const bfrag8*)(pAh + (K0));     rAh1 = *(const bfrag8*)(pAh + (K0) + 8); \
        rAl0 = *(const bfrag8*)(pAl + (K0));     rAl1 = *(const bfrag8*)(pAl + (K0) + 8); \
        rBh0 = *(const bfrag8*)(pBh + (K0));     rBh1 = *(const bfrag8*)(pBh + (K0) + 8); \
        rBl0 = *(const bfrag8*)(pBl + (K0));     rBl1 = *(const bfrag8*)(pBl + (K0) + 8); \
    } while (0)

    LOADSTEP(0);
    facc4 acc[4][4] = {};
#pragma unroll
    for (int s = 0; s < 8; s++) {
        *(bfrag8*)&As[0][sr][sc]     = rAh0;  *(bfrag8*)&As[0][sr][sc + 8] = rAh1;
        *(bfrag8*)&As[1][sr][sc]     = rAl0;  *(bfrag8*)&As[1][sr][sc + 8] = rAl1;
        *(bfrag8*)&Bs[0][sr][sc]     = rBh0;  *(bfrag8*)&Bs[0][sr][sc + 8] = rBh1;
        *(bfrag8*)&Bs[1][sr][sc]     = rBl0;  *(bfrag8*)&Bs[1][sr][sc + 8] = rBl1;
        __syncthreads();
        if (s < 7) LOADSTEP((s + 1) * 32);
        bfrag8 a[2][4], b[2][4];
#pragma unroll
        for (int t = 0; t < 4; t++) {
            a[0][t] = *(const bfrag8*)&As[0][wm + t * 16 + l15][lk];
            a[1][t] = *(const bfrag8*)&As[1][wm + t * 16 + l15][lk];
            b[0][t] = *(const bfrag8*)&Bs[0][wn + t * 16 + l15][lk];
            b[1][t] = *(const bfrag8*)&Bs[1][wn + t * 16 + l15][lk];
        }
#pragma unroll
        for (int mt = 0; mt < 4; mt++)
#pragma unroll
            for (int nt = 0; nt < 4; nt++) {
                acc[mt][nt] = __builtin_amdgcn_mfma_f32_16x16x32_bf16(a[0][mt], b[0][nt], acc[mt][nt], 0, 0, 0);
                acc[mt][nt] = __builtin_amdgcn_mfma_f32_16x16x32_bf16(a[0][mt], b[1][nt], acc[mt][nt], 0, 0, 0);
                acc[mt][nt] = __builtin_amdgcn_mfma_f32_16x16x32_bf16(a[1][mt], b[0][nt], acc[mt][nt], 0, 0, 0);
            }
        __syncthreads();
    }
#undef LOADSTEP

    const int r4 = (lane >> 4) * 4;
#pragma unroll
    for (int mt = 0; mt < 4; mt++) {
#pragma unroll
        for (int nt = 0; nt < 4; nt++) {
            int col = wn + nt * 16 + l15;
            float bias = bl[col];
#pragma unroll
            for (int r = 0; r < 4; r++) {
                int grow = m0 + wm + mt * 16 + r4 + r;
                if (grow < N_NODES) {
                    float v = fmaxf(acc[mt][nt][r] + bias, 0.f);
                    ushort h, l;
                    fsplit(v, h, l);
                    Hhi[(size_t)grow * 256 + 128 + col] = h;
                    Hlo[(size_t)grow * 256 + 128 + col] = l;
                }
            }
        }
    }
}

__global__ __launch_bounds__(256) void k_head(const ushort* __restrict__ Ahi,
                                              const ushort* __restrict__ Alo,
                                              const int* __restrict__ gstart,
                                              const int* __restrict__ root,
                                              const float* __restrict__ wcls,
                                              const float* __restrict__ bcls,
                                              float* __restrict__ out) {
    __shared__ float gm[128];
    __shared__ float part[128];
    __shared__ float red[8];
    const int g = blockIdx.x, t = threadIdx.x;
    const int c = t & 127, p = t >> 7;
    int s = gstart[g], e = gstart[g + 1];
    float sum = 0.f;
    for (int n = s + p; n < e; n += 2) {
        size_t o = (size_t)n * 256 + 128 + c;
        sum += bf2f(Ahi[o]) + bf2f(Alo[o]);
    }
    if (p) part[c] = sum;
    __syncthreads();
    if (!p) gm[c] = (sum + part[c]) / fmaxf((float)(e - s), 1.0f);
    __syncthreads();
    float v;
    if (t < 128) {
        size_t o = (size_t)root[g] * 256 + 128 + t;
        v = bf2f(Ahi[o]) + bf2f(Alo[o]);
    } else {
        v = gm[t - 128];
    }
    float p0 = v * wcls[t];
    float p1 = v * wcls[256 + t];
#pragma unroll
    for (int off = 32; off; off >>= 1) {
        p0 += __shfl_down(p0, off);
        p1 += __shfl_down(p1, off);
    }
    int wid = t >> 6;
    if ((t & 63) == 0) { red[wid] = p0; red[4 + wid] = p1; }
    __syncthreads();
    if (t == 0) {
        out[g * 2 + 0] = red[0] + red[1] + red[2] + red[3] + bcls[0];
        out[g * 2 + 1] = red[4] + red[5] + red[6] + red[7] + bcls[1];
    }
}

// ---------------------------------------------------------------- launch
extern "C" void kernel_launch(void* const* d_in, const int* in_sizes, int n_in,
                              void* d_out, int out_size, void* d_ws, size_t ws_size,
                              hipStream_t stream) {
    const float* x = (const float*)d_in[0];
    const int* ei = (const int*)d_in[1];
    const int* src = ei;
    const int* tgt = ei + N_EDGES;
    const int* root = (const int*)d_in[2];
    const int* batch = (const int*)d_in[3];
    WPtrs wp;
    wp.wl[0] = (const float*)d_in[4];  wp.wr[0] = (const float*)d_in[6];
    wp.wl[1] = (const float*)d_in[7];  wp.wr[1] = (const float*)d_in[9];
    wp.wl[2] = (const float*)d_in[10]; wp.wr[2] = (const float*)d_in[12];
    wp.wl[3] = (const float*)d_in[13]; wp.wr[3] = (const float*)d_in[15];
    const float* blv[4] = {(const float*)d_in[5], (const float*)d_in[8],
                           (const float*)d_in[11], (const float*)d_in[14]};
    const float* wcls = (const float*)d_in[16];
    const float* bcls = (const float*)d_in[17];
    float* out = (float*)d_out;

    // workspace carve-up (256-wide A tables: cols 0..127 agg, 128..255 h; in-place)
    ushort* Ahi = (ushort*)d_ws;                      // 50000*256 bf16
    ushort* Alo = Ahi + (size_t)N_NODES * 256;        // 50000*256
    ushort* BTh = Alo + (size_t)N_NODES * 256;        // 4*128*256
    ushort* BTl = BTh + 4 * 128 * 256;                // 4*128*256
    int* deg = (int*)(BTl + 4 * 128 * 256);           // 50000
    int* fill = deg + N_NODES;                        // 50000 (adjacent)
    float* dinv = (float*)(fill + N_NODES);           // 50000
    int* rowptr = (int*)(dinv + N_NODES);             // 50001
    int* csr_src = rowptr + N_NODES + 1;              // 600000
    int* bsum = csr_src + N_EDGES;                    // 196
    int* gstart = bsum + 256;                         // 257

    MegaP p;
    p.x = x; p.src = src; p.tgt = tgt; p.root = root; p.batch = batch;
    p.wp = wp;
    p.bl[0] = blv[0]; p.bl[1] = blv[1]; p.bl[2] = blv[2]; p.bl[3] = blv[3];
    p.wcls = wcls; p.bcls = bcls;
    p.Ahi = Ahi; p.Alo = Alo; p.BTh = BTh; p.BTl = BTl;
    p.deg = deg; p.fill = fill; p.dinv = dinv;
    p.rowptr = rowptr; p.csr_src = csr_src; p.bsum = bsum; p.gstart = gstart;
    p.out = out;

    void* args[] = {&p};
    hipError_t st = hipLaunchCooperativeKernel((const void*)k_mega, dim3(GBLK),
                                               dim3(256), args, 0, stream);
    if (st != hipSuccess) {
        (void)hipGetLastError();   // clear sticky error, fall back to multi-kernel path
        hipMemsetAsync(deg, 0, 2 * N_NODES * sizeof(int), stream);
        k_prep<<<PB_DEG + PB_XS + PB_WS + 1, 256, 0, stream>>>(
            tgt, deg, x, Ahi, Alo, wp, BTh, BTl, batch, gstart);
        k_scan1<<<NB, 256, 0, stream>>>(deg, bsum, dinv);
        k_scan2<<<NB, 256, 0, stream>>>(deg, bsum, rowptr);
        k_fill<<<(N_EDGES + 255) / 256, 256, 0, stream>>>(src, tgt, rowptr, fill, csr_src);
        for (int l = 0; l < 4; l++) {
            k_gather<<<(N_NODES + 7) / 8, 256, 0, stream>>>(Ahi, Alo, Ahi, Alo,
                                                            csr_src, rowptr, dinv);
            k_gemm<<<(N_NODES + 127) / 128, 256, 0, stream>>>(
                Ahi, Alo, BTh + l * 32768, BTl + l * 32768, blv[l], Ahi, Alo);
        }
        k_head<<<N_GRAPHS, 256, 0, stream>>>(Ahi, Alo, gstart, root, wcls, bcls, out);
    }
}

// Round 12
// 500.544 us; speedup vs baseline: 4.5265x; 4.5265x over previous
//
#include <hip/hip_runtime.h>
#include <hip/hip_bf16.h>

#define N_NODES 50000
#define N_EDGES 600000
#define N_GRAPHS 256
#define C 128
#define NB 196            // ceil(N_NODES/256) scan blocks
// k_prep block ranges
#define PB_DEG 2344       // ceil(600000/256)
#define PB_XS  6250       // 50000*32/256
#define PB_WS  512        // 131072/256

typedef unsigned short ushort;
typedef unsigned int uint;
typedef __attribute__((ext_vector_type(8))) short bfrag8;
typedef __attribute__((ext_vector_type(4))) float facc4;

// bf16 helpers (bit-level, RNE)
__device__ __forceinline__ ushort f2bf(float v) {
    uint u = __float_as_uint(v);
    u += 0x7FFFu + ((u >> 16) & 1u);
    return (ushort)(u >> 16);
}
__device__ __forceinline__ float bf2f(ushort u) {
    return __uint_as_float(((uint)u) << 16);
}
__device__ __forceinline__ void fsplit(float v, ushort& h, ushort& l) {
    h = f2bf(v);
    l = f2bf(v - bf2f(h));
}

struct WPtrs { const float* wl[4]; const float* wr[4]; };

// ---------------------------------------------------------------- k_prep: deg atomics + xsplit + wsplit + gstart (range-partitioned)
__global__ __launch_bounds__(256) void k_prep(const int* __restrict__ tgt,
                                              int* __restrict__ deg,
                                              const float* __restrict__ x,
                                              ushort* __restrict__ Ahi,
                                              ushort* __restrict__ Alo,
                                              WPtrs wp,
                                              ushort* __restrict__ BTh,
                                              ushort* __restrict__ BTl,
                                              const int* __restrict__ batch,
                                              int* __restrict__ gstart) {
    const int b = blockIdx.x, t = threadIdx.x;
    if (b < PB_DEG) {
        int e = b * 256 + t;
        if (e < N_EDGES) atomicAdd(&deg[tgt[e]], 1);
    } else if (b < PB_DEG + PB_XS) {
        int gid = (b - PB_DEG) * 256 + t;      // < 1600000 exactly
        int n = gid >> 5, c4 = (gid & 31) << 2;
        float4 v = *(const float4*)(x + (size_t)n * C + c4);
        ushort4 h, l;
        fsplit(v.x, h.x, l.x); fsplit(v.y, h.y, l.y);
        fsplit(v.z, h.z, l.z); fsplit(v.w, h.w, l.w);
        *(ushort4*)(Ahi + (size_t)n * 256 + 128 + c4) = h;
        *(ushort4*)(Alo + (size_t)n * 256 + 128 + c4) = l;
    } else if (b < PB_DEG + PB_XS + PB_WS) {
        int gid = (b - PB_DEG - PB_XS) * 256 + t;   // < 131072 exactly
        int l = gid >> 15;
        int rem = gid & 32767;
        int n = rem >> 8, k = rem & 255;
        float v = (k < 128) ? wp.wl[l][n * 128 + k] : wp.wr[l][n * 128 + (k - 128)];
        ushort h, lo;
        fsplit(v, h, lo);
        BTh[gid] = h;
        BTl[gid] = lo;
    } else {
        // gstart: g = t (0..255) binary search on sorted batch; plus sentinel
        int g = t;
        int lo = 0, hi = N_NODES;
        while (lo < hi) {
            int mid = (lo + hi) >> 1;
            if (batch[mid] < g) lo = mid + 1;
            else hi = mid;
        }
        gstart[g] = lo;
        if (t == 0) gstart[N_GRAPHS] = N_NODES;
    }
}

// ---------------------------------------------------------------- scan stage 1: block sums (+ dinv fused)
__global__ __launch_bounds__(256) void k_scan1(const int* __restrict__ deg,
                                               int* __restrict__ bsum,
                                               float* __restrict__ dinv) {
    __shared__ int ws[4];
    int idx = blockIdx.x * 256 + threadIdx.x;
    int v = (idx < N_NODES) ? deg[idx] : 0;
    if (idx < N_NODES) dinv[idx] = 1.0f / fmaxf((float)v, 1.0f);
    int s = v;
#pragma unroll
    for (int off = 1; off < 64; off <<= 1) s += __shfl_xor(s, off);
    if ((threadIdx.x & 63) == 0) ws[threadIdx.x >> 6] = s;
    __syncthreads();
    if (threadIdx.x == 0) bsum[blockIdx.x] = ws[0] + ws[1] + ws[2] + ws[3];
}

// ---------------------------------------------------------------- scan stage 2: global offset (recomputed per block) + local scan -> rowptr
__global__ __launch_bounds__(256) void k_scan2(const int* __restrict__ deg,
                                               const int* __restrict__ bsum,
                                               int* __restrict__ rowptr) {
    __shared__ int red[4];
    __shared__ int ws[4];
    const int b = blockIdx.x, t = threadIdx.x;
    const int lane = t & 63, w = t >> 6;
    int bv = (t < NB && t < b) ? bsum[t] : 0;
#pragma unroll
    for (int off = 1; off < 64; off <<= 1) bv += __shfl_xor(bv, off);
    if (lane == 0) red[w] = bv;
    __syncthreads();
    const int boff = red[0] + red[1] + red[2] + red[3];
    int idx = b * 256 + t;
    int v = (idx < N_NODES) ? deg[idx] : 0;
    int incl = v;
#pragma unroll
    for (int off = 1; off < 64; off <<= 1) {
        int u = __shfl_up(incl, off);
        if (lane >= off) incl += u;
    }
    if (lane == 63) ws[w] = incl;
    __syncthreads();
    int wo = 0;
    if (w > 0) wo += ws[0];
    if (w > 1) wo += ws[1];
    if (w > 2) wo += ws[2];
    if (idx < N_NODES) rowptr[idx] = boff + wo + incl - v;
    if (b == 0 && t == 0) rowptr[N_NODES] = N_EDGES;
}

// ---------------------------------------------------------------- CSR fill
__global__ void k_fill(const int* __restrict__ src, const int* __restrict__ tgt,
                       const int* __restrict__ rowptr, int* __restrict__ fill,
                       int* __restrict__ csr_src) {
    int e = blockIdx.x * blockDim.x + threadIdx.x;
    if (e >= N_EDGES) return;
    int d = tgt[e];
    int pos = atomicAdd(&fill[d], 1);
    csr_src[rowptr[d] + pos] = src[e];
}

// ---------------------------------------------------------------- gather-mean on planes (champion body; dinv hoisted pre-loop)
// 32 lanes per node, ushort4 loads, 4-edge unroll
// reads cols 128..255 (h of prev layer, hi+lo), writes cols 0..127 (agg split)
__global__ __launch_bounds__(256) void k_gather(const ushort* __restrict__ Ahi_r,
                                                const ushort* __restrict__ Alo_r,
                                                ushort* __restrict__ Ahi_w,
                                                ushort* __restrict__ Alo_w,
                                                const int* __restrict__ csr_src,
                                                const int* __restrict__ rowptr,
                                                const float* __restrict__ dinv) {
    int node = blockIdx.x * 8 + (threadIdx.x >> 5);
    if (node >= N_NODES) return;
    int lane = threadIdx.x & 31;
    int c4 = lane << 2;
    int s = rowptr[node], e = rowptr[node + 1];
    float sc = dinv[node];              // hoisted: latency hides under the loop
    float a0 = 0.f, a1 = 0.f, a2 = 0.f, a3 = 0.f;
    int j = s;
    for (; j + 3 < e; j += 4) {
        int s0 = csr_src[j], s1 = csr_src[j + 1];
        int s2 = csr_src[j + 2], s3 = csr_src[j + 3];
        ushort4 h0 = *(const ushort4*)(Ahi_r + (size_t)s0 * 256 + 128 + c4);
        ushort4 l0 = *(const ushort4*)(Alo_r + (size_t)s0 * 256 + 128 + c4);
        ushort4 h1 = *(const ushort4*)(Ahi_r + (size_t)s1 * 256 + 128 + c4);
        ushort4 l1 = *(const ushort4*)(Alo_r + (size_t)s1 * 256 + 128 + c4);
        ushort4 h2 = *(const ushort4*)(Ahi_r + (size_t)s2 * 256 + 128 + c4);
        ushort4 l2 = *(const ushort4*)(Alo_r + (size_t)s2 * 256 + 128 + c4);
        ushort4 h3 = *(const ushort4*)(Ahi_r + (size_t)s3 * 256 + 128 + c4);
        ushort4 l3 = *(const ushort4*)(Alo_r + (size_t)s3 * 256 + 128 + c4);
        a0 += (bf2f(h0.x) + bf2f(l0.x)) + (bf2f(h1.x) + bf2f(l1.x))
            + (bf2f(h2.x) + bf2f(l2.x)) + (bf2f(h3.x) + bf2f(l3.x));
        a1 += (bf2f(h0.y) + bf2f(l0.y)) + (bf2f(h1.y) + bf2f(l1.y))
            + (bf2f(h2.y) + bf2f(l2.y)) + (bf2f(h3.y) + bf2f(l3.y));
        a2 += (bf2f(h0.z) + bf2f(l0.z)) + (bf2f(h1.z) + bf2f(l1.z))
            + (bf2f(h2.z) + bf2f(l2.z)) + (bf2f(h3.z) + bf2f(l3.z));
        a3 += (bf2f(h0.w) + bf2f(l0.w)) + (bf2f(h1.w) + bf2f(l1.w))
            + (bf2f(h2.w) + bf2f(l2.w)) + (bf2f(h3.w) + bf2f(l3.w));
    }
    for (; j < e; j++) {
        int s0 = csr_src[j];
        ushort4 h0 = *(const ushort4*)(Ahi_r + (size_t)s0 * 256 + 128 + c4);
        ushort4 l0 = *(const ushort4*)(Alo_r + (size_t)s0 * 256 + 128 + c4);
        a0 += bf2f(h0.x) + bf2f(l0.x);
        a1 += bf2f(h0.y) + bf2f(l0.y);
        a2 += bf2f(h0.z) + bf2f(l0.z);
        a3 += bf2f(h0.w) + bf2f(l0.w);
    }
    a0 *= sc; a1 *= sc; a2 *= sc; a3 *= sc;
    ushort4 h, l;
    fsplit(a0, h.x, l.x); fsplit(a1, h.y, l.y);
    fsplit(a2, h.z, l.z); fsplit(a3, h.w, l.w);
    *(ushort4*)(Ahi_w + (size_t)node * 256 + c4) = h;
    *(ushort4*)(Alo_w + (size_t)node * 256 + c4) = l;
}

// ---------------------------------------------------------------- split-bf16 MFMA GEMM (champion body)
// D = Ahi·Bhi + Ahi·Blo + Alo·Bhi over K=256; 128x128 block, 4 waves (2x2 of 64x64),
// register-prefetch pipelined staging; pad 38 (odd 19-word stride, 38912B LDS).
__global__ __launch_bounds__(256) void k_gemm(const ushort* __restrict__ Ahi,
                                              const ushort* __restrict__ Alo,
                                              const ushort* __restrict__ BTh,
                                              const ushort* __restrict__ BTl,
                                              const float* __restrict__ bl,
                                              ushort* __restrict__ Hhi,
                                              ushort* __restrict__ Hlo) {
    __shared__ short As[2][128][38];
    __shared__ short Bs[2][128][38];
    const int tid = threadIdx.x;
    const int wave = tid >> 6, lane = tid & 63;
    const int m0 = blockIdx.x * 128;
    const int wm = (wave & 1) * 64;
    const int wn = (wave >> 1) * 64;
    const int l15 = lane & 15, lk = (lane >> 4) * 8;

    const int sr = tid >> 1;
    const int sc = (tid & 1) * 16;
    int garow = m0 + sr; if (garow >= N_NODES) garow = N_NODES - 1;
    const ushort* pAh = Ahi + (size_t)garow * 256 + sc;
    const ushort* pAl = Alo + (size_t)garow * 256 + sc;
    const ushort* pBh = BTh + sr * 256 + sc;
    const ushort* pBl = BTl + sr * 256 + sc;

    bfrag8 rAh0, rAh1, rAl0, rAl1, rBh0, rBh1, rBl0, rBl1;
#define LOADSTEP(K0) do { \
        rAh0 = *(const bfrag8*)(pAh + (K0));     rAh1 = *(const bfrag8*)(pAh + (K0) + 8); \
        rAl0 = *(const bfrag8*)(pAl + (K0));     rAl1 = *(const bfrag8*)(pAl + (K0) + 8); \
        rBh0 = *(const bfrag8*)(pBh + (K0));     rBh1 = *(const bfrag8*)(pBh + (K0) + 8); \
        rBl0 = *(const bfrag8*)(pBl + (K0));     rBl1 = *(const bfrag8*)(pBl + (K0) + 8); \
    } while (0)

    LOADSTEP(0);
    facc4 acc[4][4] = {};
#pragma unroll
    for (int s = 0; s < 8; s++) {
        *(bfrag8*)&As[0][sr][sc]     = rAh0;  *(bfrag8*)&As[0][sr][sc + 8] = rAh1;
        *(bfrag8*)&As[1][sr][sc]     = rAl0;  *(bfrag8*)&As[1][sr][sc + 8] = rAl1;
        *(bfrag8*)&Bs[0][sr][sc]     = rBh0;  *(bfrag8*)&Bs[0][sr][sc + 8] = rBh1;
        *(bfrag8*)&Bs[1][sr][sc]     = rBl0;  *(bfrag8*)&Bs[1][sr][sc + 8] = rBl1;
        __syncthreads();
        if (s < 7) LOADSTEP((s + 1) * 32);   // prefetch next K-step (overlaps MFMAs below)
        bfrag8 a[2][4], b[2][4];
#pragma unroll
        for (int t = 0; t < 4; t++) {
            a[0][t] = *(const bfrag8*)&As[0][wm + t * 16 + l15][lk];
            a[1][t] = *(const bfrag8*)&As[1][wm + t * 16 + l15][lk];
            b[0][t] = *(const bfrag8*)&Bs[0][wn + t * 16 + l15][lk];
            b[1][t] = *(const bfrag8*)&Bs[1][wn + t * 16 + l15][lk];
        }
#pragma unroll
        for (int mt = 0; mt < 4; mt++)
#pragma unroll
            for (int nt = 0; nt < 4; nt++) {
                acc[mt][nt] = __builtin_amdgcn_mfma_f32_16x16x32_bf16(a[0][mt], b[0][nt], acc[mt][nt], 0, 0, 0);
                acc[mt][nt] = __builtin_amdgcn_mfma_f32_16x16x32_bf16(a[0][mt], b[1][nt], acc[mt][nt], 0, 0, 0);
                acc[mt][nt] = __builtin_amdgcn_mfma_f32_16x16x32_bf16(a[1][mt], b[0][nt], acc[mt][nt], 0, 0, 0);
            }
        __syncthreads();
    }
#undef LOADSTEP

    // epilogue: bias + relu + split, write cols 128..255
    const int r4 = (lane >> 4) * 4;
#pragma unroll
    for (int mt = 0; mt < 4; mt++) {
#pragma unroll
        for (int nt = 0; nt < 4; nt++) {
            int col = wn + nt * 16 + l15;
            float bias = bl[col];
#pragma unroll
            for (int r = 0; r < 4; r++) {
                int grow = m0 + wm + mt * 16 + r4 + r;
                if (grow < N_NODES) {
                    float v = fmaxf(acc[mt][nt][r] + bias, 0.f);
                    ushort h, l;
                    fsplit(v, h, l);
                    Hhi[(size_t)grow * 256 + 128 + col] = h;
                    Hlo[(size_t)grow * 256 + 128 + col] = l;
                }
            }
        }
    }
}

// ---------------------------------------------------------------- k_head: mean-pool + classifier fused (one block per graph)
__global__ __launch_bounds__(256) void k_head(const ushort* __restrict__ Ahi,
                                              const ushort* __restrict__ Alo,
                                              const int* __restrict__ gstart,
                                              const int* __restrict__ root,
                                              const float* __restrict__ wcls,
                                              const float* __restrict__ bcls,
                                              float* __restrict__ out) {
    __shared__ float gm[128];
    __shared__ float part[128];
    __shared__ float red[8];
    const int g = blockIdx.x, t = threadIdx.x;
    const int c = t & 127, p = t >> 7;
    int s = gstart[g], e = gstart[g + 1];
    float sum = 0.f;
    for (int n = s + p; n < e; n += 2) {
        size_t o = (size_t)n * 256 + 128 + c;
        sum += bf2f(Ahi[o]) + bf2f(Alo[o]);
    }
    if (p) part[c] = sum;
    __syncthreads();
    if (!p) gm[c] = (sum + part[c]) / fmaxf((float)(e - s), 1.0f);
    __syncthreads();
    float v;
    if (t < 128) {
        size_t o = (size_t)root[g] * 256 + 128 + t;
        v = bf2f(Ahi[o]) + bf2f(Alo[o]);
    } else {
        v = gm[t - 128];
    }
    float p0 = v * wcls[t];
    float p1 = v * wcls[256 + t];
#pragma unroll
    for (int off = 32; off; off >>= 1) {
        p0 += __shfl_down(p0, off);
        p1 += __shfl_down(p1, off);
    }
    int wid = t >> 6;
    if ((t & 63) == 0) { red[wid] = p0; red[4 + wid] = p1; }
    __syncthreads();
    if (t == 0) {
        out[g * 2 + 0] = red[0] + red[1] + red[2] + red[3] + bcls[0];
        out[g * 2 + 1] = red[4] + red[5] + red[6] + red[7] + bcls[1];
    }
}

// ---------------------------------------------------------------- launch
extern "C" void kernel_launch(void* const* d_in, const int* in_sizes, int n_in,
                              void* d_out, int out_size, void* d_ws, size_t ws_size,
                              hipStream_t stream) {
    const float* x = (const float*)d_in[0];
    const int* ei = (const int*)d_in[1];
    const int* src = ei;
    const int* tgt = ei + N_EDGES;
    const int* root = (const int*)d_in[2];
    const int* batch = (const int*)d_in[3];
    WPtrs wp;
    wp.wl[0] = (const float*)d_in[4];  wp.wr[0] = (const float*)d_in[6];
    wp.wl[1] = (const float*)d_in[7];  wp.wr[1] = (const float*)d_in[9];
    wp.wl[2] = (const float*)d_in[10]; wp.wr[2] = (const float*)d_in[12];
    wp.wl[3] = (const float*)d_in[13]; wp.wr[3] = (const float*)d_in[15];
    const float* blv[4] = {(const float*)d_in[5], (const float*)d_in[8],
                           (const float*)d_in[11], (const float*)d_in[14]};
    const float* wcls = (const float*)d_in[16];
    const float* bcls = (const float*)d_in[17];
    float* out = (float*)d_out;

    // workspace carve-up (256-wide A tables: cols 0..127 agg, 128..255 h; in-place)
    ushort* Ahi = (ushort*)d_ws;                      // 50000*256 bf16
    ushort* Alo = Ahi + (size_t)N_NODES * 256;        // 50000*256
    ushort* BTh = Alo + (size_t)N_NODES * 256;        // 4*128*256
    ushort* BTl = BTh + 4 * 128 * 256;                // 4*128*256
    int* deg = (int*)(BTl + 4 * 128 * 256);           // 50000
    int* fill = deg + N_NODES;                        // 50000 (adjacent: one memset)
    float* dinv = (float*)(fill + N_NODES);           // 50000
    int* rowptr = (int*)(dinv + N_NODES);             // 50001
    int* csr_src = rowptr + N_NODES + 1;              // 600000
    int* bsum = csr_src + N_EDGES;                    // 196
    int* gstart = bsum + 256;                         // 257

    hipMemsetAsync(deg, 0, 2 * N_NODES * sizeof(int), stream);  // deg + fill
    k_prep<<<PB_DEG + PB_XS + PB_WS + 1, 256, 0, stream>>>(
        tgt, deg, x, Ahi, Alo, wp, BTh, BTl, batch, gstart);
    k_scan1<<<NB, 256, 0, stream>>>(deg, bsum, dinv);
    k_scan2<<<NB, 256, 0, stream>>>(deg, bsum, rowptr);
    k_fill<<<(N_EDGES + 255) / 256, 256, 0, stream>>>(src, tgt, rowptr, fill, csr_src);

    for (int l = 0; l < 4; l++) {
        k_gather<<<(N_NODES + 7) / 8, 256, 0, stream>>>(Ahi, Alo, Ahi, Alo,
                                                        csr_src, rowptr, dinv);
        k_gemm<<<(N_NODES + 127) / 128, 256, 0, stream>>>(
            Ahi, Alo, BTh + l * 32768, BTl + l * 32768, blv[l], Ahi, Alo);
    }
    k_head<<<N_GRAPHS, 256, 0, stream>>>(Ahi, Alo, gstart, root, wcls, bcls, out);
}

// Round 13
// 483.612 us; speedup vs baseline: 4.6850x; 1.0350x over previous
//
#include <hip/hip_runtime.h>
#include <hip/hip_bf16.h>

#define N_NODES 50000
#define N_EDGES 600000
#define N_GRAPHS 256
#define C 128
#define NB 196            // ceil(N_NODES/256) scan blocks
// k_prep block ranges
#define PB_DEG 2344       // ceil(600000/256)
#define PB_XS  6250       // 50000*32/256
#define PB_WS  512        // 131072/256

typedef unsigned short ushort;
typedef unsigned int uint;
typedef __attribute__((ext_vector_type(8))) short bfrag8;
typedef __attribute__((ext_vector_type(4))) float facc4;

// bf16 helpers (bit-level, RNE)
__device__ __forceinline__ ushort f2bf(float v) {
    uint u = __float_as_uint(v);
    u += 0x7FFFu + ((u >> 16) & 1u);
    return (ushort)(u >> 16);
}
__device__ __forceinline__ float bf2f(ushort u) {
    return __uint_as_float(((uint)u) << 16);
}
__device__ __forceinline__ void fsplit(float v, ushort& h, ushort& l) {
    h = f2bf(v);
    l = f2bf(v - bf2f(h));
}

struct WPtrs { const float* wl[4]; const float* wr[4]; };

// ---------------------------------------------------------------- k_prep: deg atomics + xsplit + wsplit + gstart (range-partitioned)
__global__ __launch_bounds__(256) void k_prep(const int* __restrict__ tgt,
                                              int* __restrict__ deg,
                                              const float* __restrict__ x,
                                              ushort* __restrict__ Ahi,
                                              ushort* __restrict__ Alo,
                                              WPtrs wp,
                                              ushort* __restrict__ BTh,
                                              ushort* __restrict__ BTl,
                                              const int* __restrict__ batch,
                                              int* __restrict__ gstart) {
    const int b = blockIdx.x, t = threadIdx.x;
    if (b < PB_DEG) {
        int e = b * 256 + t;
        if (e < N_EDGES) atomicAdd(&deg[tgt[e]], 1);
    } else if (b < PB_DEG + PB_XS) {
        int gid = (b - PB_DEG) * 256 + t;      // < 1600000 exactly
        int n = gid >> 5, c4 = (gid & 31) << 2;
        float4 v = *(const float4*)(x + (size_t)n * C + c4);
        ushort4 h, l;
        fsplit(v.x, h.x, l.x); fsplit(v.y, h.y, l.y);
        fsplit(v.z, h.z, l.z); fsplit(v.w, h.w, l.w);
        *(ushort4*)(Ahi + (size_t)n * 256 + 128 + c4) = h;
        *(ushort4*)(Alo + (size_t)n * 256 + 128 + c4) = l;
    } else if (b < PB_DEG + PB_XS + PB_WS) {
        int gid = (b - PB_DEG - PB_XS) * 256 + t;   // < 131072 exactly
        int l = gid >> 15;
        int rem = gid & 32767;
        int n = rem >> 8, k = rem & 255;
        float v = (k < 128) ? wp.wl[l][n * 128 + k] : wp.wr[l][n * 128 + (k - 128)];
        ushort h, lo;
        fsplit(v, h, lo);
        BTh[gid] = h;
        BTl[gid] = lo;
    } else {
        // gstart: g = t (0..255) binary search on sorted batch; plus sentinel
        int g = t;
        int lo = 0, hi = N_NODES;
        while (lo < hi) {
            int mid = (lo + hi) >> 1;
            if (batch[mid] < g) lo = mid + 1;
            else hi = mid;
        }
        gstart[g] = lo;
        if (t == 0) gstart[N_GRAPHS] = N_NODES;
    }
}

// ---------------------------------------------------------------- scan stage 1: block sums (+ dinv fused)
__global__ __launch_bounds__(256) void k_scan1(const int* __restrict__ deg,
                                               int* __restrict__ bsum,
                                               float* __restrict__ dinv) {
    __shared__ int ws[4];
    int idx = blockIdx.x * 256 + threadIdx.x;
    int v = (idx < N_NODES) ? deg[idx] : 0;
    if (idx < N_NODES) dinv[idx] = 1.0f / fmaxf((float)v, 1.0f);
    int s = v;
#pragma unroll
    for (int off = 1; off < 64; off <<= 1) s += __shfl_xor(s, off);
    if ((threadIdx.x & 63) == 0) ws[threadIdx.x >> 6] = s;
    __syncthreads();
    if (threadIdx.x == 0) bsum[blockIdx.x] = ws[0] + ws[1] + ws[2] + ws[3];
}

// ---------------------------------------------------------------- scan stage 2: global offset (recomputed per block) + local scan -> rowptr
__global__ __launch_bounds__(256) void k_scan2(const int* __restrict__ deg,
                                               const int* __restrict__ bsum,
                                               int* __restrict__ rowptr) {
    __shared__ int red[4];
    __shared__ int ws[4];
    const int b = blockIdx.x, t = threadIdx.x;
    const int lane = t & 63, w = t >> 6;
    int bv = (t < NB && t < b) ? bsum[t] : 0;
#pragma unroll
    for (int off = 1; off < 64; off <<= 1) bv += __shfl_xor(bv, off);
    if (lane == 0) red[w] = bv;
    __syncthreads();
    const int boff = red[0] + red[1] + red[2] + red[3];
    int idx = b * 256 + t;
    int v = (idx < N_NODES) ? deg[idx] : 0;
    int incl = v;
#pragma unroll
    for (int off = 1; off < 64; off <<= 1) {
        int u = __shfl_up(incl, off);
        if (lane >= off) incl += u;
    }
    if (lane == 63) ws[w] = incl;
    __syncthreads();
    int wo = 0;
    if (w > 0) wo += ws[0];
    if (w > 1) wo += ws[1];
    if (w > 2) wo += ws[2];
    if (idx < N_NODES) rowptr[idx] = boff + wo + incl - v;
    if (b == 0 && t == 0) rowptr[N_NODES] = N_EDGES;
}

// ---------------------------------------------------------------- CSR fill
__global__ void k_fill(const int* __restrict__ src, const int* __restrict__ tgt,
                       const int* __restrict__ rowptr, int* __restrict__ fill,
                       int* __restrict__ csr_src) {
    int e = blockIdx.x * blockDim.x + threadIdx.x;
    if (e >= N_EDGES) return;
    int d = tgt[e];
    int pos = atomicAdd(&fill[d], 1);
    csr_src[rowptr[d] + pos] = src[e];
}

// ---------------------------------------------------------------- gather-mean on planes (champion body; dinv hoisted — verified neutral-positive r12)
// 32 lanes per node, ushort4 loads, 4-edge unroll
// reads cols 128..255 (h of prev layer, hi+lo), writes cols 0..127 (agg split)
__global__ __launch_bounds__(256) void k_gather(const ushort* __restrict__ Ahi_r,
                                                const ushort* __restrict__ Alo_r,
                                                ushort* __restrict__ Ahi_w,
                                                ushort* __restrict__ Alo_w,
                                                const int* __restrict__ csr_src,
                                                const int* __restrict__ rowptr,
                                                const float* __restrict__ dinv) {
    int node = blockIdx.x * 8 + (threadIdx.x >> 5);
    if (node >= N_NODES) return;
    int lane = threadIdx.x & 31;
    int c4 = lane << 2;
    int s = rowptr[node], e = rowptr[node + 1];
    float sc = dinv[node];              // hoisted: latency hides under the loop
    float a0 = 0.f, a1 = 0.f, a2 = 0.f, a3 = 0.f;
    int j = s;
    for (; j + 3 < e; j += 4) {
        int s0 = csr_src[j], s1 = csr_src[j + 1];
        int s2 = csr_src[j + 2], s3 = csr_src[j + 3];
        ushort4 h0 = *(const ushort4*)(Ahi_r + (size_t)s0 * 256 + 128 + c4);
        ushort4 l0 = *(const ushort4*)(Alo_r + (size_t)s0 * 256 + 128 + c4);
        ushort4 h1 = *(const ushort4*)(Ahi_r + (size_t)s1 * 256 + 128 + c4);
        ushort4 l1 = *(const ushort4*)(Alo_r + (size_t)s1 * 256 + 128 + c4);
        ushort4 h2 = *(const ushort4*)(Ahi_r + (size_t)s2 * 256 + 128 + c4);
        ushort4 l2 = *(const ushort4*)(Alo_r + (size_t)s2 * 256 + 128 + c4);
        ushort4 h3 = *(const ushort4*)(Ahi_r + (size_t)s3 * 256 + 128 + c4);
        ushort4 l3 = *(const ushort4*)(Alo_r + (size_t)s3 * 256 + 128 + c4);
        a0 += (bf2f(h0.x) + bf2f(l0.x)) + (bf2f(h1.x) + bf2f(l1.x))
            + (bf2f(h2.x) + bf2f(l2.x)) + (bf2f(h3.x) + bf2f(l3.x));
        a1 += (bf2f(h0.y) + bf2f(l0.y)) + (bf2f(h1.y) + bf2f(l1.y))
            + (bf2f(h2.y) + bf2f(l2.y)) + (bf2f(h3.y) + bf2f(l3.y));
        a2 += (bf2f(h0.z) + bf2f(l0.z)) + (bf2f(h1.z) + bf2f(l1.z))
            + (bf2f(h2.z) + bf2f(l2.z)) + (bf2f(h3.z) + bf2f(l3.z));
        a3 += (bf2f(h0.w) + bf2f(l0.w)) + (bf2f(h1.w) + bf2f(l1.w))
            + (bf2f(h2.w) + bf2f(l2.w)) + (bf2f(h3.w) + bf2f(l3.w));
    }
    for (; j < e; j++) {
        int s0 = csr_src[j];
        ushort4 h0 = *(const ushort4*)(Ahi_r + (size_t)s0 * 256 + 128 + c4);
        ushort4 l0 = *(const ushort4*)(Alo_r + (size_t)s0 * 256 + 128 + c4);
        a0 += bf2f(h0.x) + bf2f(l0.x);
        a1 += bf2f(h0.y) + bf2f(l0.y);
        a2 += bf2f(h0.z) + bf2f(l0.z);
        a3 += bf2f(h0.w) + bf2f(l0.w);
    }
    a0 *= sc; a1 *= sc; a2 *= sc; a3 *= sc;
    ushort4 h, l;
    fsplit(a0, h.x, l.x); fsplit(a1, h.y, l.y);
    fsplit(a2, h.z, l.z); fsplit(a3, h.w, l.w);
    *(ushort4*)(Ahi_w + (size_t)node * 256 + c4) = h;
    *(ushort4*)(Alo_w + (size_t)node * 256 + c4) = l;
}

// ---------------------------------------------------------------- split-bf16 MFMA GEMM (r10 champion body, pad 40 — pad 38 measured -16us total, r12)
// D = Ahi·Bhi + Ahi·Blo + Alo·Bhi over K=256; 128x128 block, 4 waves (2x2 of 64x64),
// register-prefetch pipelined staging.
__global__ __launch_bounds__(256) void k_gemm(const ushort* __restrict__ Ahi,
                                              const ushort* __restrict__ Alo,
                                              const ushort* __restrict__ BTh,
                                              const ushort* __restrict__ BTl,
                                              const float* __restrict__ bl,
                                              ushort* __restrict__ Hhi,
                                              ushort* __restrict__ Hlo) {
    __shared__ short As[2][128][40];
    __shared__ short Bs[2][128][40];
    const int tid = threadIdx.x;
    const int wave = tid >> 6, lane = tid & 63;
    const int m0 = blockIdx.x * 128;
    const int wm = (wave & 1) * 64;
    const int wn = (wave >> 1) * 64;
    const int l15 = lane & 15, lk = (lane >> 4) * 8;

    const int sr = tid >> 1;
    const int sc = (tid & 1) * 16;
    int garow = m0 + sr; if (garow >= N_NODES) garow = N_NODES - 1;
    const ushort* pAh = Ahi + (size_t)garow * 256 + sc;
    const ushort* pAl = Alo + (size_t)garow * 256 + sc;
    const ushort* pBh = BTh + sr * 256 + sc;
    const ushort* pBl = BTl + sr * 256 + sc;

    bfrag8 rAh0, rAh1, rAl0, rAl1, rBh0, rBh1, rBl0, rBl1;
#define LOADSTEP(K0) do { \
        rAh0 = *(const bfrag8*)(pAh + (K0));     rAh1 = *(const bfrag8*)(pAh + (K0) + 8); \
        rAl0 = *(const bfrag8*)(pAl + (K0));     rAl1 = *(const bfrag8*)(pAl + (K0) + 8); \
        rBh0 = *(const bfrag8*)(pBh + (K0));     rBh1 = *(const bfrag8*)(pBh + (K0) + 8); \
        rBl0 = *(const bfrag8*)(pBl + (K0));     rBl1 = *(const bfrag8*)(pBl + (K0) + 8); \
    } while (0)

    LOADSTEP(0);
    facc4 acc[4][4] = {};
#pragma unroll
    for (int s = 0; s < 8; s++) {
        *(bfrag8*)&As[0][sr][sc]     = rAh0;  *(bfrag8*)&As[0][sr][sc + 8] = rAh1;
        *(bfrag8*)&As[1][sr][sc]     = rAl0;  *(bfrag8*)&As[1][sr][sc + 8] = rAl1;
        *(bfrag8*)&Bs[0][sr][sc]     = rBh0;  *(bfrag8*)&Bs[0][sr][sc + 8] = rBh1;
        *(bfrag8*)&Bs[1][sr][sc]     = rBl0;  *(bfrag8*)&Bs[1][sr][sc + 8] = rBl1;
        __syncthreads();
        if (s < 7) LOADSTEP((s + 1) * 32);   // prefetch next K-step (overlaps MFMAs below)
        bfrag8 a[2][4], b[2][4];
#pragma unroll
        for (int t = 0; t < 4; t++) {
            a[0][t] = *(const bfrag8*)&As[0][wm + t * 16 + l15][lk];
            a[1][t] = *(const bfrag8*)&As[1][wm + t * 16 + l15][lk];
            b[0][t] = *(const bfrag8*)&Bs[0][wn + t * 16 + l15][lk];
            b[1][t] = *(const bfrag8*)&Bs[1][wn + t * 16 + l15][lk];
        }
#pragma unroll
        for (int mt = 0; mt < 4; mt++)
#pragma unroll
            for (int nt = 0; nt < 4; nt++) {
                acc[mt][nt] = __builtin_amdgcn_mfma_f32_16x16x32_bf16(a[0][mt], b[0][nt], acc[mt][nt], 0, 0, 0);
                acc[mt][nt] = __builtin_amdgcn_mfma_f32_16x16x32_bf16(a[0][mt], b[1][nt], acc[mt][nt], 0, 0, 0);
                acc[mt][nt] = __builtin_amdgcn_mfma_f32_16x16x32_bf16(a[1][mt], b[0][nt], acc[mt][nt], 0, 0, 0);
            }
        __syncthreads();
    }
#undef LOADSTEP

    // epilogue: bias + relu + split, write cols 128..255
    const int r4 = (lane >> 4) * 4;
#pragma unroll
    for (int mt = 0; mt < 4; mt++) {
#pragma unroll
        for (int nt = 0; nt < 4; nt++) {
            int col = wn + nt * 16 + l15;
            float bias = bl[col];
#pragma unroll
            for (int r = 0; r < 4; r++) {
                int grow = m0 + wm + mt * 16 + r4 + r;
                if (grow < N_NODES) {
                    float v = fmaxf(acc[mt][nt][r] + bias, 0.f);
                    ushort h, l;
                    fsplit(v, h, l);
                    Hhi[(size_t)grow * 256 + 128 + col] = h;
                    Hlo[(size_t)grow * 256 + 128 + col] = l;
                }
            }
        }
    }
}

// ---------------------------------------------------------------- k_head: mean-pool + classifier fused (one block per graph)
__global__ __launch_bounds__(256) void k_head(const ushort* __restrict__ Ahi,
                                              const ushort* __restrict__ Alo,
                                              const int* __restrict__ gstart,
                                              const int* __restrict__ root,
                                              const float* __restrict__ wcls,
                                              const float* __restrict__ bcls,
                                              float* __restrict__ out) {
    __shared__ float gm[128];
    __shared__ float part[128];
    __shared__ float red[8];
    const int g = blockIdx.x, t = threadIdx.x;
    const int c = t & 127, p = t >> 7;
    int s = gstart[g], e = gstart[g + 1];
    float sum = 0.f;
    for (int n = s + p; n < e; n += 2) {
        size_t o = (size_t)n * 256 + 128 + c;
        sum += bf2f(Ahi[o]) + bf2f(Alo[o]);
    }
    if (p) part[c] = sum;
    __syncthreads();
    if (!p) gm[c] = (sum + part[c]) / fmaxf((float)(e - s), 1.0f);
    __syncthreads();
    float v;
    if (t < 128) {
        size_t o = (size_t)root[g] * 256 + 128 + t;
        v = bf2f(Ahi[o]) + bf2f(Alo[o]);
    } else {
        v = gm[t - 128];
    }
    float p0 = v * wcls[t];
    float p1 = v * wcls[256 + t];
#pragma unroll
    for (int off = 32; off; off >>= 1) {
        p0 += __shfl_down(p0, off);
        p1 += __shfl_down(p1, off);
    }
    int wid = t >> 6;
    if ((t & 63) == 0) { red[wid] = p0; red[4 + wid] = p1; }
    __syncthreads();
    if (t == 0) {
        out[g * 2 + 0] = red[0] + red[1] + red[2] + red[3] + bcls[0];
        out[g * 2 + 1] = red[4] + red[5] + red[6] + red[7] + bcls[1];
    }
}

// ---------------------------------------------------------------- launch
extern "C" void kernel_launch(void* const* d_in, const int* in_sizes, int n_in,
                              void* d_out, int out_size, void* d_ws, size_t ws_size,
                              hipStream_t stream) {
    const float* x = (const float*)d_in[0];
    const int* ei = (const int*)d_in[1];
    const int* src = ei;
    const int* tgt = ei + N_EDGES;
    const int* root = (const int*)d_in[2];
    const int* batch = (const int*)d_in[3];
    WPtrs wp;
    wp.wl[0] = (const float*)d_in[4];  wp.wr[0] = (const float*)d_in[6];
    wp.wl[1] = (const float*)d_in[7];  wp.wr[1] = (const float*)d_in[9];
    wp.wl[2] = (const float*)d_in[10]; wp.wr[2] = (const float*)d_in[12];
    wp.wl[3] = (const float*)d_in[13]; wp.wr[3] = (const float*)d_in[15];
    const float* blv[4] = {(const float*)d_in[5], (const float*)d_in[8],
                           (const float*)d_in[11], (const float*)d_in[14]};
    const float* wcls = (const float*)d_in[16];
    const float* bcls = (const float*)d_in[17];
    float* out = (float*)d_out;

    // workspace carve-up (256-wide A tables: cols 0..127 agg, 128..255 h; in-place)
    ushort* Ahi = (ushort*)d_ws;                      // 50000*256 bf16
    ushort* Alo = Ahi + (size_t)N_NODES * 256;        // 50000*256
    ushort* BTh = Alo + (size_t)N_NODES * 256;        // 4*128*256
    ushort* BTl = BTh + 4 * 128 * 256;                // 4*128*256
    int* deg = (int*)(BTl + 4 * 128 * 256);           // 50000
    int* fill = deg + N_NODES;                        // 50000 (adjacent: one memset)
    float* dinv = (float*)(fill + N_NODES);           // 50000
    int* rowptr = (int*)(dinv + N_NODES);             // 50001
    int* csr_src = rowptr + N_NODES + 1;              // 600000
    int* bsum = csr_src + N_EDGES;                    // 196
    int* gstart = bsum + 256;                         // 257

    hipMemsetAsync(deg, 0, 2 * N_NODES * sizeof(int), stream);  // deg + fill
    k_prep<<<PB_DEG + PB_XS + PB_WS + 1, 256, 0, stream>>>(
        tgt, deg, x, Ahi, Alo, wp, BTh, BTl, batch, gstart);
    k_scan1<<<NB, 256, 0, stream>>>(deg, bsum, dinv);
    k_scan2<<<NB, 256, 0, stream>>>(deg, bsum, rowptr);
    k_fill<<<(N_EDGES + 255) / 256, 256, 0, stream>>>(src, tgt, rowptr, fill, csr_src);

    for (int l = 0; l < 4; l++) {
        k_gather<<<(N_NODES + 7) / 8, 256, 0, stream>>>(Ahi, Alo, Ahi, Alo,
                                                        csr_src, rowptr, dinv);
        k_gemm<<<(N_NODES + 127) / 128, 256, 0, stream>>>(
            Ahi, Alo, BTh + l * 32768, BTl + l * 32768, blv[l], Ahi, Alo);
    }
    k_head<<<N_GRAPHS, 256, 0, stream>>>(Ahi, Alo, gstart, root, wcls, bcls, out);
}